// Round 12
// baseline (413.343 us; speedup 1.0000x reference)
//
#include <hip/hip_runtime.h>
#include <math.h>

#define EPS 1e-6f

typedef __attribute__((ext_vector_type(4))) float f32x4;

constexpr int B    = 8;
constexpr int F    = 64;
constexpr int C    = 16;
constexpr int L    = 65536;      // 256*256
constexpr int G4   = L / 4;      // float4 elements per (b, f) slice
constexpr int TPB  = 256;
constexpr int NREP = 8;          // atomic-target replicas

// Stage 1: partials num[b,c] = sum_l (e2 - 2*dot)*r, den[b,c] = sum_l r.
// ws layout: float ws[NREP][2][2][B][C] -> [rep][term][num/den][b][c]
//
// R5 family (proven correct + best register discipline) with two deltas:
// (1) float4 loads: 1 KB per latency exposure instead of 512 B — halves the
//     stall count per byte moved;
// (2) 2-slot cur/nxt rotation, #pragma unroll 2 (swap becomes role-alternation,
//     NO full unroll — that was R4's register explosion): next f-row's load
//     issues before current row's 36-FMA compute, so the compiler's natural
//     wait-before-first-use leaves ~2 KB in flight per wave.
// Budget: dot[8][4]=32 + e2[4] + cur/nxt 8 + addressing ~= 56 VGPR, under the
// launch_bounds(256,8) 64-cap. 2048 blocks = exactly 8 blocks/CU.
__global__ __launch_bounds__(TPB, 8)
void cross_partial_kernel(const float* __restrict__ embed1,
                          const float* __restrict__ rids1,
                          const float* __restrict__ embed2,
                          const float* __restrict__ rids2,
                          const float* __restrict__ codebook,
                          float* __restrict__ ws)
{
    const int tid   = threadIdx.x;
    const int lane  = tid & 63;
    const int wid   = tid >> 6;
    const int gslot = wid >> 1;          // which 256-float chunk of the block's 512
    const int term  = blockIdx.z;        // 0: (embed_1, r_ids_2), 1: (embed_2, r_ids_1)
    const int b     = blockIdx.y;
    const float* eptr = (term == 0) ? embed1 : embed2;
    const float* rptr = (term == 0) ? rids2  : rids1;

    // wave-uniform c-base in an SGPR so codebook reads scalarize (s_load)
    const int c0 = __builtin_amdgcn_readfirstlane((wid & 1) * 8);

    const int fbase = blockIdx.x * 512 + gslot * 256;    // float index in [0, L)
    const f32x4* eb = (const f32x4*)(eptr + (size_t)b * F * L + fbase) + lane;
    const f32x4* rb = (const f32x4*)(rptr + (size_t)b * C * L + fbase) + lane;

    float dot[8][4], e2[4];
    #pragma unroll
    for (int k = 0; k < 4; ++k) e2[k] = 0.f;
    #pragma unroll
    for (int j = 0; j < 8; ++j)
        #pragma unroll
        for (int k = 0; k < 4; ++k) dot[j][k] = 0.f;

    // 2-slot rotation: load f+1 while computing f
    f32x4 cur = eb[0];
    #pragma unroll 2
    for (int f = 0; f < F - 1; ++f) {
        f32x4 nxt = eb[(size_t)(f + 1) * G4];
        #pragma unroll
        for (int k = 0; k < 4; ++k)
            e2[k] = fmaf(cur[k], cur[k], e2[k]);
        #pragma unroll
        for (int j = 0; j < 8; ++j) {
            const float w = codebook[f * C + c0 + j];   // SGPR broadcast
            #pragma unroll
            for (int k = 0; k < 4; ++k)
                dot[j][k] = fmaf(cur[k], w, dot[j][k]);
        }
        cur = nxt;
    }
    {   // f = F-1
        #pragma unroll
        for (int k = 0; k < 4; ++k)
            e2[k] = fmaf(cur[k], cur[k], e2[k]);
        #pragma unroll
        for (int j = 0; j < 8; ++j) {
            const float w = codebook[(F - 1) * C + c0 + j];
            #pragma unroll
            for (int k = 0; k < 4; ++k)
                dot[j][k] = fmaf(cur[k], w, dot[j][k]);
        }
    }

    // epilogue: r loads in two batches of 4 (16 regs), fold, wave-reduce
    __shared__ float part[4][2][8];
    #pragma unroll 1
    for (int jb = 0; jb < 8; jb += 4) {
        f32x4 rv[4];
        #pragma unroll
        for (int u = 0; u < 4; ++u)
            rv[u] = rb[(size_t)(c0 + jb + u) * G4];
        __builtin_amdgcn_sched_barrier(0);
        #pragma unroll
        for (int u = 0; u < 4; ++u) {
            const int j = jb + u;
            float num = fmaf(-2.f, dot[j][0], e2[0]) * rv[u][0]
                      + fmaf(-2.f, dot[j][1], e2[1]) * rv[u][1]
                      + fmaf(-2.f, dot[j][2], e2[2]) * rv[u][2]
                      + fmaf(-2.f, dot[j][3], e2[3]) * rv[u][3];
            float den = (rv[u][0] + rv[u][1]) + (rv[u][2] + rv[u][3]);
            #pragma unroll
            for (int off = 32; off > 0; off >>= 1) {
                num += __shfl_down(num, off, 64);
                den += __shfl_down(den, off, 64);
            }
            if (lane == 0) { part[wid][0][j] = num; part[wid][1][j] = den; }
        }
    }
    __syncthreads();

    // combine the two gslot waves per c, one atomic per value
    if (tid < 2 * C) {
        const int p = tid >> 4, c = tid & 15;
        const int chalf = c >> 3, j = c & 7;
        const float v = part[chalf][p][j] + part[chalf + 2][p][j];
        const int rep = blockIdx.x & (NREP - 1);
        atomicAdd(ws + ((((size_t)rep * 2 + term) * 2 + p) * B + b) * C + c, v);
    }
}

// Stage 2: single block. cross = (num + cb2[c]*den)/(den+EPS); plus dist/reg losses.
__global__ __launch_bounds__(256)
void finalize_kernel(const float* __restrict__ codebook,
                     const float* __restrict__ ws,
                     float* __restrict__ out)
{
    __shared__ float cbs[F * C];
    __shared__ float cb2[C];
    __shared__ float red[256];
    __shared__ float redv[256];
    const int tid = threadIdx.x;
    ((float4*)cbs)[tid] = ((const float4*)codebook)[tid];
    __syncthreads();
    if (tid < C) {
        float s = 0.f;
        for (int f = 0; f < F; ++f) { const float v = cbs[f * C + tid]; s = fmaf(v, v, s); }
        cb2[tid] = s;
    }
    __syncthreads();

    // l_cross: 256 entries = [term(2)][b(8)][c(16)]
    {
        const int term = tid >> 7, rem = tid & 127;
        const int b = rem >> 4, c = rem & 15;
        float num = 0.f, den = 0.f;
        for (int rep = 0; rep < NREP; ++rep) {
            num += ws[((((size_t)rep * 2 + term) * 2 + 0) * B + b) * C + c];
            den += ws[((((size_t)rep * 2 + term) * 2 + 1) * B + b) * C + c];
        }
        const bool valid = (den != 0.f);
        red[tid]  = valid ? (num + cb2[c] * den) / (den + EPS) : 0.f;
        redv[tid] = valid ? 1.f : 0.f;
    }
    __syncthreads();
    if (tid == 0) {
        float s0 = 0.f, n0 = 0.f, s1 = 0.f, n1 = 0.f;
        for (int i = 0;   i < 128; ++i) { s0 += red[i]; n0 += redv[i]; }
        for (int i = 128; i < 256; ++i) { s1 += red[i]; n1 += redv[i]; }
        out[0] = s0 / n0 + s1 / n1;
    }
    __syncthreads();

    // l_dist: 256 (ci,cj) pairs, diagonal included exactly as reference
    {
        const int ci = tid & 15, cj = tid >> 4;
        float sq = 0.f;
        for (int f = 0; f < F; ++f) {
            const float d = cbs[f * C + ci] - cbs[f * C + cj];
            sq = fmaf(d, d, sq);
        }
        const float dist = (sq > 0.f) ? sqrtf(sq) : 0.f;
        const float h = fmaxf(2.f * 1.0f - dist, 0.f);
        red[tid] = h * h;
    }
    __syncthreads();
    if (tid == 0) {
        float s = 0.f;
        for (int i = 0; i < 256; ++i) s += red[i];
        out[1] = s / (2.f * C * (C - 1));
        float rg = 0.f;
        for (int c = 0; c < C; ++c) rg += sqrtf(cb2[c]);
        out[2] = rg / C;
    }
}

extern "C" void kernel_launch(void* const* d_in, const int* in_sizes, int n_in,
                              void* d_out, int out_size, void* d_ws, size_t ws_size,
                              hipStream_t stream)
{
    const float* e1 = (const float*)d_in[0];
    const float* r1 = (const float*)d_in[1];
    const float* e2 = (const float*)d_in[2];
    const float* r2 = (const float*)d_in[3];
    const float* cb = (const float*)d_in[4];
    float* out = (float*)d_out;
    float* ws  = (float*)d_ws;

    // zero the NREP*2*2*B*C accumulator block (16 KB)
    hipMemsetAsync(ws, 0, (size_t)NREP * 2 * 2 * B * C * sizeof(float), stream);

    // block covers 512 floats (2 chunks x 64 lanes x float4); wave pairs split C 8+8
    dim3 grid(L / 512, B, 2);   // 128 x 8 x 2 = 2048 blocks = exactly 8 blocks/CU
    cross_partial_kernel<<<grid, TPB, 0, stream>>>(e1, r1, e2, r2, cb, ws);
    finalize_kernel<<<1, 256, 0, stream>>>(cb, ws, out);
}

// Round 13
// 77.712 us; speedup vs baseline: 5.3189x; 5.3189x over previous
//
#include <hip/hip_runtime.h>
#include <math.h>

#define EPS 1e-6f

constexpr int B    = 8;
constexpr int F    = 64;
constexpr int C    = 16;
constexpr int L    = 65536;      // 256*256
constexpr int TPB  = 256;
constexpr int NREP = 8;          // atomic-target replicas
constexpr int BLKF = 256;        // l-floats per block
constexpr int FB   = 8;          // f-rows per LDS tile (8 KB)
constexpr int NT   = F / FB;     // 8 tiles

// Stage 1: partials num[b,c] = sum_l (e2 - 2*dot)*r, den[b,c] = sum_l r.
// ws layout: float ws[NREP][2][2][B][C] -> [rep][term][num/den][b][c]
//
// R8 structure, restored verbatim (best measured: 77.3 us total bench).
// Double-buffered LDS tile pipeline, reg-staged coalesced float4 loads
// (normal cached path -> L3 reuse, no DMA fetch amplification), one
// __syncthreads per tile. 12 rounds of evidence: every attempt to deepen
// the per-wave load pipeline beyond this (reg batches, sched_barrier pins,
// sched_group_barrier, hand vmcnt asm, global_load_lds DMA, unroll-2
// rotation) failed by collapse, spill, fetch amplification, or corruption.
// This kernel runs at ~4.8 TB/s effective demand = 76% of the 6.3 TB/s
// copy-bench ceiling, with VALU work (~15 us) fully hidden.
__global__ __launch_bounds__(TPB, 8)
void cross_partial_kernel(const float* __restrict__ embed1,
                          const float* __restrict__ rids1,
                          const float* __restrict__ embed2,
                          const float* __restrict__ rids2,
                          const float* __restrict__ codebook,
                          float* __restrict__ ws)
{
    __shared__ __align__(16) float buf[2][FB * BLKF];   // 2 x 8 KB
    __shared__ float part[4][2][8];

    const int tid   = threadIdx.x;
    const int lane  = tid & 63;
    const int wid   = tid >> 6;
    const int gslot = wid >> 1;            // which half of the 256-float row
    const int term  = blockIdx.z;
    const int b     = blockIdx.y;
    const float* eptr = (term == 0) ? embed1 : embed2;
    const float* rptr = (term == 0) ? rids2  : rids1;

    const int c0 = __builtin_amdgcn_readfirstlane((wid & 1) * 8);   // SGPR c-base

    const int lbase = blockIdx.x * BLKF;
    const float* eslice = eptr + (size_t)b * F * L + lbase;
    const int myidx = gslot * 64 + lane;   // float2 index within a row [0,128)

    float dotx[8], doty[8];
    #pragma unroll
    for (int j = 0; j < 8; ++j) { dotx[j] = 0.f; doty[j] = 0.f; }
    float e2x = 0.f, e2y = 0.f;

    // prologue: reg-stage tile 0 (each wave: 2 f-rows, 1 KB each), write to LDS
    {
        const float* g = eslice + (size_t)(wid * 2) * L + lane * 4;
        const float4 pa = *(const float4*)g;
        const float4 pb = *(const float4*)(g + L);
        ((float4*)&buf[0][(wid * 2 + 0) * BLKF])[lane] = pa;
        ((float4*)&buf[0][(wid * 2 + 1) * BLKF])[lane] = pb;
    }
    __syncthreads();

    #pragma unroll 1
    for (int t = 0; t < NT; ++t) {
        // phase A: issue next tile's loads (coalesced float4, cached path)
        float4 na, nb;
        const bool more = (t + 1 < NT);
        if (more) {
            const float* g = eslice + (size_t)((t + 1) * FB + wid * 2) * L + lane * 4;
            na = *(const float4*)g;
            nb = *(const float4*)(g + L);
        }
        __builtin_amdgcn_sched_barrier(0);   // pin: loads issue before compute

        // phase B: compute tile t from LDS (HBM latency hides under this)
        const float2* lb = (const float2*)buf[t & 1];
        #pragma unroll
        for (int u = 0; u < FB; ++u) {
            const float2 ev = lb[u * 128 + myidx];
            e2x = fmaf(ev.x, ev.x, e2x);
            e2y = fmaf(ev.y, ev.y, e2y);
            #pragma unroll
            for (int j = 0; j < 8; ++j) {
                const float w = codebook[(t * FB + u) * C + c0 + j];  // SGPR bcast
                dotx[j] = fmaf(ev.x, w, dotx[j]);
                doty[j] = fmaf(ev.y, w, doty[j]);
            }
        }

        // phase C: write staged tile into the other buffer; one barrier per tile
        // (prev iter's barrier already guarantees everyone finished reading it)
        if (more) {
            float* d = &buf[(t + 1) & 1][(wid * 2) * BLKF];
            ((float4*)d)[lane] = na;
            ((float4*)(d + BLKF))[lane] = nb;
        }
        __syncthreads();
    }

    // epilogue: 8 r float2 loads in flight, fold, wave-reduce, block-combine
    const float* rslice = rptr + (size_t)b * C * L + lbase;
    {
        float2 rv[8];
        #pragma unroll
        for (int j = 0; j < 8; ++j)
            rv[j] = *(const float2*)(rslice + (size_t)(c0 + j) * L + myidx * 2);
        __builtin_amdgcn_sched_barrier(0);
        #pragma unroll
        for (int j = 0; j < 8; ++j) {
            float num = fmaf(-2.f, dotx[j], e2x) * rv[j].x
                      + fmaf(-2.f, doty[j], e2y) * rv[j].y;
            float den = rv[j].x + rv[j].y;
            #pragma unroll
            for (int off = 32; off > 0; off >>= 1) {
                num += __shfl_down(num, off, 64);
                den += __shfl_down(den, off, 64);
            }
            if (lane == 0) { part[wid][0][j] = num; part[wid][1][j] = den; }
        }
    }
    __syncthreads();

    if (tid < 2 * C) {
        const int p = tid >> 4, c = tid & 15;
        const int chalf = c >> 3, j = c & 7;
        const float v = part[chalf][p][j] + part[chalf + 2][p][j];
        const int rep = blockIdx.x & (NREP - 1);
        atomicAdd(ws + ((((size_t)rep * 2 + term) * 2 + p) * B + b) * C + c, v);
    }
}

// Stage 2: single block. cross = (num + cb2[c]*den)/(den+EPS); plus dist/reg losses.
__global__ __launch_bounds__(256)
void finalize_kernel(const float* __restrict__ codebook,
                     const float* __restrict__ ws,
                     float* __restrict__ out)
{
    __shared__ float cbs[F * C];
    __shared__ float cb2[C];
    __shared__ float red[256];
    __shared__ float redv[256];
    const int tid = threadIdx.x;
    ((float4*)cbs)[tid] = ((const float4*)codebook)[tid];
    __syncthreads();
    if (tid < C) {
        float s = 0.f;
        for (int f = 0; f < F; ++f) { const float v = cbs[f * C + tid]; s = fmaf(v, v, s); }
        cb2[tid] = s;
    }
    __syncthreads();

    // l_cross: 256 entries = [term(2)][b(8)][c(16)]
    {
        const int term = tid >> 7, rem = tid & 127;
        const int b = rem >> 4, c = rem & 15;
        float num = 0.f, den = 0.f;
        for (int rep = 0; rep < NREP; ++rep) {
            num += ws[((((size_t)rep * 2 + term) * 2 + 0) * B + b) * C + c];
            den += ws[((((size_t)rep * 2 + term) * 2 + 1) * B + b) * C + c];
        }
        const bool valid = (den != 0.f);
        red[tid]  = valid ? (num + cb2[c] * den) / (den + EPS) : 0.f;
        redv[tid] = valid ? 1.f : 0.f;
    }
    __syncthreads();
    if (tid == 0) {
        float s0 = 0.f, n0 = 0.f, s1 = 0.f, n1 = 0.f;
        for (int i = 0;   i < 128; ++i) { s0 += red[i]; n0 += redv[i]; }
        for (int i = 128; i < 256; ++i) { s1 += red[i]; n1 += redv[i]; }
        out[0] = s0 / n0 + s1 / n1;
    }
    __syncthreads();

    // l_dist: 256 (ci,cj) pairs, diagonal included exactly as reference
    {
        const int ci = tid & 15, cj = tid >> 4;
        float sq = 0.f;
        for (int f = 0; f < F; ++f) {
            const float d = cbs[f * C + ci] - cbs[f * C + cj];
            sq = fmaf(d, d, sq);
        }
        const float dist = (sq > 0.f) ? sqrtf(sq) : 0.f;
        const float h = fmaxf(2.f * 1.0f - dist, 0.f);
        red[tid] = h * h;
    }
    __syncthreads();
    if (tid == 0) {
        float s = 0.f;
        for (int i = 0; i < 256; ++i) s += red[i];
        out[1] = s / (2.f * C * (C - 1));
        float rg = 0.f;
        for (int c = 0; c < C; ++c) rg += sqrtf(cb2[c]);
        out[2] = rg / C;
    }
}

extern "C" void kernel_launch(void* const* d_in, const int* in_sizes, int n_in,
                              void* d_out, int out_size, void* d_ws, size_t ws_size,
                              hipStream_t stream)
{
    const float* e1 = (const float*)d_in[0];
    const float* r1 = (const float*)d_in[1];
    const float* e2 = (const float*)d_in[2];
    const float* r2 = (const float*)d_in[3];
    const float* cb = (const float*)d_in[4];
    float* out = (float*)d_out;
    float* ws  = (float*)d_ws;

    // zero the NREP*2*2*B*C accumulator block (16 KB)
    hipMemsetAsync(ws, 0, (size_t)NREP * 2 * 2 * B * C * sizeof(float), stream);

    dim3 grid(L / BLKF, B, 2);   // 256 x 8 x 2 = 4096 blocks
    cross_partial_kernel<<<grid, TPB, 0, stream>>>(e1, r1, e2, r2, cb, ws);
    finalize_kernel<<<1, 256, 0, stream>>>(cb, ws, out);
}

// Round 14
// 76.936 us; speedup vs baseline: 5.3725x; 1.0101x over previous
//
#include <hip/hip_runtime.h>
#include <math.h>

#define EPS 1e-6f

constexpr int B    = 8;
constexpr int F    = 64;
constexpr int C    = 16;
constexpr int L    = 65536;      // 256*256
constexpr int TPB  = 256;
constexpr int NREP = 8;          // atomic-target replicas
constexpr int BLKF = 256;        // l-floats per block
constexpr int FB   = 8;          // f-rows per LDS tile (8 KB)
constexpr int NT   = F / FB;     // 8 tiles

// Stage 1: partials num[b,c] = sum_l (e2 - 2*dot)*r, den[b,c] = sum_l r.
// ws layout: float ws[NREP][2][2][B][C] -> [rep][term][num/den][b][c]
//
// R8 structure (best measured, reproduced twice at 77.3/77.7 us) + ONE delta:
// T1 XCD-aware blockIdx.x swizzle. Theory: five structurally different
// schedules all plateau at ~4.8 TB/s because consecutive l-chunks (adjacent
// 1 KB granules of the same DRAM pages / L2 lines) are dispatched round-robin
// to DIFFERENT XCDs, so every XCD L2 and DRAM channel sees maximally
// interleaved strided streams. Remap lchunk = (bx%8)*32 + bx/8 (bijective,
// 256%8==0): each XCD owns a contiguous 32-chunk region per (term,b) plane
// -> clustered L2 fills, contiguous DRAM bursts.
__global__ __launch_bounds__(TPB, 8)
void cross_partial_kernel(const float* __restrict__ embed1,
                          const float* __restrict__ rids1,
                          const float* __restrict__ embed2,
                          const float* __restrict__ rids2,
                          const float* __restrict__ codebook,
                          float* __restrict__ ws)
{
    __shared__ __align__(16) float buf[2][FB * BLKF];   // 2 x 8 KB
    __shared__ float part[4][2][8];

    const int tid   = threadIdx.x;
    const int lane  = tid & 63;
    const int wid   = tid >> 6;
    const int gslot = wid >> 1;            // which half of the 256-float row
    const int term  = blockIdx.z;
    const int b     = blockIdx.y;
    const float* eptr = (term == 0) ? embed1 : embed2;
    const float* rptr = (term == 0) ? rids2  : rids1;

    const int c0 = __builtin_amdgcn_readfirstlane((wid & 1) * 8);   // SGPR c-base

    // T1: XCD-aware swizzle. Dispatch slot bx goes to XCD bx%8; give that XCD
    // the lchunk from a contiguous 32-chunk run.
    const int lchunk = (blockIdx.x & 7) * 32 + (blockIdx.x >> 3);
    const int lbase  = lchunk * BLKF;
    const float* eslice = eptr + (size_t)b * F * L + lbase;
    const int myidx = gslot * 64 + lane;   // float2 index within a row [0,128)

    float dotx[8], doty[8];
    #pragma unroll
    for (int j = 0; j < 8; ++j) { dotx[j] = 0.f; doty[j] = 0.f; }
    float e2x = 0.f, e2y = 0.f;

    // prologue: reg-stage tile 0 (each wave: 2 f-rows, 1 KB each), write to LDS
    {
        const float* g = eslice + (size_t)(wid * 2) * L + lane * 4;
        const float4 pa = *(const float4*)g;
        const float4 pb = *(const float4*)(g + L);
        ((float4*)&buf[0][(wid * 2 + 0) * BLKF])[lane] = pa;
        ((float4*)&buf[0][(wid * 2 + 1) * BLKF])[lane] = pb;
    }
    __syncthreads();

    #pragma unroll 1
    for (int t = 0; t < NT; ++t) {
        // phase A: issue next tile's loads (coalesced float4, cached path)
        float4 na, nb;
        const bool more = (t + 1 < NT);
        if (more) {
            const float* g = eslice + (size_t)((t + 1) * FB + wid * 2) * L + lane * 4;
            na = *(const float4*)g;
            nb = *(const float4*)(g + L);
        }
        __builtin_amdgcn_sched_barrier(0);   // pin: loads issue before compute

        // phase B: compute tile t from LDS (HBM latency hides under this)
        const float2* lb = (const float2*)buf[t & 1];
        #pragma unroll
        for (int u = 0; u < FB; ++u) {
            const float2 ev = lb[u * 128 + myidx];
            e2x = fmaf(ev.x, ev.x, e2x);
            e2y = fmaf(ev.y, ev.y, e2y);
            #pragma unroll
            for (int j = 0; j < 8; ++j) {
                const float w = codebook[(t * FB + u) * C + c0 + j];  // SGPR bcast
                dotx[j] = fmaf(ev.x, w, dotx[j]);
                doty[j] = fmaf(ev.y, w, doty[j]);
            }
        }

        // phase C: write staged tile into the other buffer; one barrier per tile
        if (more) {
            float* d = &buf[(t + 1) & 1][(wid * 2) * BLKF];
            ((float4*)d)[lane] = na;
            ((float4*)(d + BLKF))[lane] = nb;
        }
        __syncthreads();
    }

    // epilogue: 8 r float2 loads in flight, fold, wave-reduce, block-combine
    const float* rslice = rptr + (size_t)b * C * L + lbase;
    {
        float2 rv[8];
        #pragma unroll
        for (int j = 0; j < 8; ++j)
            rv[j] = *(const float2*)(rslice + (size_t)(c0 + j) * L + myidx * 2);
        __builtin_amdgcn_sched_barrier(0);
        #pragma unroll
        for (int j = 0; j < 8; ++j) {
            float num = fmaf(-2.f, dotx[j], e2x) * rv[j].x
                      + fmaf(-2.f, doty[j], e2y) * rv[j].y;
            float den = rv[j].x + rv[j].y;
            #pragma unroll
            for (int off = 32; off > 0; off >>= 1) {
                num += __shfl_down(num, off, 64);
                den += __shfl_down(den, off, 64);
            }
            if (lane == 0) { part[wid][0][j] = num; part[wid][1][j] = den; }
        }
    }
    __syncthreads();

    if (tid < 2 * C) {
        const int p = tid >> 4, c = tid & 15;
        const int chalf = c >> 3, j = c & 7;
        const float v = part[chalf][p][j] + part[chalf + 2][p][j];
        const int rep = blockIdx.x & (NREP - 1);
        atomicAdd(ws + ((((size_t)rep * 2 + term) * 2 + p) * B + b) * C + c, v);
    }
}

// Stage 2: single block. cross = (num + cb2[c]*den)/(den+EPS); plus dist/reg losses.
__global__ __launch_bounds__(256)
void finalize_kernel(const float* __restrict__ codebook,
                     const float* __restrict__ ws,
                     float* __restrict__ out)
{
    __shared__ float cbs[F * C];
    __shared__ float cb2[C];
    __shared__ float red[256];
    __shared__ float redv[256];
    const int tid = threadIdx.x;
    ((float4*)cbs)[tid] = ((const float4*)codebook)[tid];
    __syncthreads();
    if (tid < C) {
        float s = 0.f;
        for (int f = 0; f < F; ++f) { const float v = cbs[f * C + tid]; s = fmaf(v, v, s); }
        cb2[tid] = s;
    }
    __syncthreads();

    // l_cross: 256 entries = [term(2)][b(8)][c(16)]
    {
        const int term = tid >> 7, rem = tid & 127;
        const int b = rem >> 4, c = rem & 15;
        float num = 0.f, den = 0.f;
        for (int rep = 0; rep < NREP; ++rep) {
            num += ws[((((size_t)rep * 2 + term) * 2 + 0) * B + b) * C + c];
            den += ws[((((size_t)rep * 2 + term) * 2 + 1) * B + b) * C + c];
        }
        const bool valid = (den != 0.f);
        red[tid]  = valid ? (num + cb2[c] * den) / (den + EPS) : 0.f;
        redv[tid] = valid ? 1.f : 0.f;
    }
    __syncthreads();
    if (tid == 0) {
        float s0 = 0.f, n0 = 0.f, s1 = 0.f, n1 = 0.f;
        for (int i = 0;   i < 128; ++i) { s0 += red[i]; n0 += redv[i]; }
        for (int i = 128; i < 256; ++i) { s1 += red[i]; n1 += redv[i]; }
        out[0] = s0 / n0 + s1 / n1;
    }
    __syncthreads();

    // l_dist: 256 (ci,cj) pairs, diagonal included exactly as reference
    {
        const int ci = tid & 15, cj = tid >> 4;
        float sq = 0.f;
        for (int f = 0; f < F; ++f) {
            const float d = cbs[f * C + ci] - cbs[f * C + cj];
            sq = fmaf(d, d, sq);
        }
        const float dist = (sq > 0.f) ? sqrtf(sq) : 0.f;
        const float h = fmaxf(2.f * 1.0f - dist, 0.f);
        red[tid] = h * h;
    }
    __syncthreads();
    if (tid == 0) {
        float s = 0.f;
        for (int i = 0; i < 256; ++i) s += red[i];
        out[1] = s / (2.f * C * (C - 1));
        float rg = 0.f;
        for (int c = 0; c < C; ++c) rg += sqrtf(cb2[c]);
        out[2] = rg / C;
    }
}

extern "C" void kernel_launch(void* const* d_in, const int* in_sizes, int n_in,
                              void* d_out, int out_size, void* d_ws, size_t ws_size,
                              hipStream_t stream)
{
    const float* e1 = (const float*)d_in[0];
    const float* r1 = (const float*)d_in[1];
    const float* e2 = (const float*)d_in[2];
    const float* r2 = (const float*)d_in[3];
    const float* cb = (const float*)d_in[4];
    float* out = (float*)d_out;
    float* ws  = (float*)d_ws;

    // zero the NREP*2*2*B*C accumulator block (16 KB)
    hipMemsetAsync(ws, 0, (size_t)NREP * 2 * 2 * B * C * sizeof(float), stream);

    dim3 grid(L / BLKF, B, 2);   // 256 x 8 x 2 = 4096 blocks
    cross_partial_kernel<<<grid, TPB, 0, stream>>>(e1, r1, e2, r2, cb, ws);
    finalize_kernel<<<1, 256, 0, stream>>>(cb, ws, out);
}